// Round 12
// baseline (271.059 us; speedup 1.0000x reference)
//
#include <hip/hip_runtime.h>

typedef unsigned short u16;
typedef unsigned char u8;
typedef unsigned int u32;
typedef __attribute__((ext_vector_type(4))) float f32x4;
typedef __attribute__((ext_vector_type(16))) float f32x16;
typedef __attribute__((ext_vector_type(8))) __bf16 bf16x8;
typedef __attribute__((ext_vector_type(4))) int i32x4;
typedef __attribute__((ext_vector_type(16))) int i32x16;

__device__ __forceinline__ u16 f2bf(float f) {
  u32 u = __float_as_uint(f);
  u32 r = (u + 0x7fffu + ((u >> 16) & 1u)) >> 16;
  return (u16)r;
}

__device__ __forceinline__ float load_thr(const int* p) {
  int iv = *p;
  float fv = __int_as_float(iv);
  if (fv >= 1.0f && fv <= 1.0e6f) return fv;
  return (float)iv;
}

__device__ __forceinline__ void gload_lds16(const void* g, void* l) {
  __builtin_amdgcn_global_load_lds(
      (const __attribute__((address_space(1))) void*)g,
      (__attribute__((address_space(3))) void*)l, 16, 0, 0);
}

// ---------------- colmax over rows of x ----------------
__global__ void k_init_cm(u32* cm, int K) {
  int i = blockIdx.x * 256 + threadIdx.x;
  if (i < K) cm[i] = 0u;
}

__global__ __launch_bounds__(256) void k_colmax(const float* __restrict__ x,
                                                u32* __restrict__ cm, int M,
                                                int K, int rpb) {
  int c4 = blockIdx.x * 256 + threadIdx.x;
  int r0 = blockIdx.y * rpb;
  int r1 = r0 + rpb;
  if (r1 > M) r1 = M;
  f32x4 mx = {0.f, 0.f, 0.f, 0.f};
  for (int r = r0; r < r1; ++r) {
    f32x4 v = *(const f32x4*)&x[(size_t)r * K + (size_t)c4 * 4];
#pragma unroll
    for (int i = 0; i < 4; ++i) mx[i] = fmaxf(mx[i], fabsf(v[i]));
  }
#pragma unroll
  for (int i = 0; i < 4; ++i)
    atomicMax(&cm[c4 * 4 + i], __float_as_uint(mx[i]));
}

// ---------------- ordered outlier-column compaction (1 wave) -------------
__global__ void k_ocols(const u32* __restrict__ cm, const int* __restrict__ thr_i,
                        int K, int* __restrict__ meta) {
  int lane = threadIdx.x;  // 64 threads
  float thr = load_thr(thr_i);
  const float* cmf = (const float*)cm;
  int per = K >> 6;
  int base = lane * per;
  int c = 0;
  for (int i = 0; i < per; ++i) c += (cmf[base + i] > thr) ? 1 : 0;
  int inc = c;
  for (int off = 1; off < 64; off <<= 1) {
    int t = __shfl_up(inc, off);
    if (lane >= off) inc += t;
  }
  int excl = inc - c;
  int total = __shfl(inc, 63);
  if (lane == 0) meta[0] = total < 64 ? total : 64;
  int idx = excl;
  for (int i = 0; i < per; ++i) {
    if (cmf[base + i] > thr) {
      if (idx < 64) meta[1 + idx] = base + i;
      idx++;
    }
  }
  for (int j = total + lane; j < 64; j += 64) meta[1 + j] = -1;
}

// ---------------- row-wise int8 quant (TILED output) + outlier gather ----
// qdst int8 tiled [rows/32][K/32][32][32] (1KB blocks, row-major in block).
__global__ __launch_bounds__(256) void k_quant8(
    const float* __restrict__ src, const u32* __restrict__ cm,
    const int* __restrict__ thr_i, const int* __restrict__ meta,
    char* __restrict__ qdst, float* __restrict__ sdst, u16* __restrict__ odst,
    int K, int zero_outlier) {
  int row = blockIdx.x;
  int tid = threadIdx.x;
  float thr = load_thr(thr_i);
  const float* sr = src + (size_t)row * K;
  const float* cmf = (const float*)cm;

  float v[16];
  u32 omask = 0;
  float lmax = 0.f;
#pragma unroll
  for (int j = 0; j < 4; ++j) {
    int c4 = j * 256 + tid;
    f32x4 val = *(const f32x4*)&sr[c4 * 4];
    f32x4 cv = *(const f32x4*)&cmf[c4 * 4];
#pragma unroll
    for (int i = 0; i < 4; ++i) {
      float xv = val[i];
      v[j * 4 + i] = xv;
      bool is_out = cv[i] > thr;
      if (is_out) omask |= 1u << (j * 4 + i);
      if (!is_out || !zero_outlier) lmax = fmaxf(lmax, fabsf(xv));
    }
  }
  float m = lmax;
#pragma unroll
  for (int off = 32; off >= 1; off >>= 1) m = fmaxf(m, __shfl_down(m, off));
  __shared__ float red[4];
  int lane = tid & 63, wv = tid >> 6;
  if (lane == 0) red[wv] = m;
  __syncthreads();
  float rm = fmaxf(fmaxf(red[0], red[1]), fmaxf(red[2], red[3]));
  float s = fmaxf(rm / 127.0f, 1e-8f);

  // tiled write: u32 index = ((row>>5)*(K>>5)+(c4>>3))*256 + (row&31)*8 + (c4&7)
  u32* qt = (u32*)qdst;
  size_t rowpart = (size_t)(row >> 5) * (K >> 5) * 256 + (size_t)(row & 31) * 8;
#pragma unroll
  for (int j = 0; j < 4; ++j) {
    int c4 = j * 256 + tid;
    u32 pk = 0;
#pragma unroll
    for (int i = 0; i < 4; ++i) {
      float xv = v[j * 4 + i];
      int iq;
      if (zero_outlier && (omask & (1u << (j * 4 + i)))) {
        iq = 0;
      } else {
        float q = rintf(xv / s);  // round-half-even, matches jnp.round
        q = fminf(fmaxf(q, -127.f), 127.f);
        iq = (int)q;
      }
      pk |= ((u32)(u8)(char)iq) << (8 * i);
    }
    qt[rowpart + (size_t)(c4 >> 3) * 256 + (c4 & 7)] = pk;
  }
  if (tid == 0) sdst[row] = s;
  if (tid < 64) {
    int n_out = meta[0];
    int oc = meta[1 + tid];
    u16 ov = 0;
    if (tid < n_out && oc >= 0) ov = f2bf(sr[oc]);
    odst[(size_t)row * 64 + tid] = ov;
  }
}

// ---------------- i8 GEMM: 128x256 block, 8 waves 2Mx4N, 64x64/wave ------
// out = sx[m]*sw[n]*(qx @ qw^T) + x_o @ w_o^T + bias
// acc = 64 AGPR + ~90 VGPR -> <=128 unified/wave -> 2 blocks/CU (the r6-r11
// plateau was 1 block/CU with acc=128). Both operands through LDS in tiled
// 1KB-block layout (coalesced staging, 2-way-free frag reads). BK=64,
// 24KB/buf dbuf (48KB); 1 phase per K-tile, counted vmcnt(3).
__global__ __launch_bounds__(512, 4) void k_gemm_i8(
    const char* __restrict__ qx, const char* __restrict__ qw,
    const float* __restrict__ sx, const float* __restrict__ sw,
    const float* __restrict__ bias, const char* __restrict__ xo,
    const char* __restrict__ wo, float* __restrict__ out, int M, int N,
    int K) {
  extern __shared__ char lds_raw[];  // 48 KB: buf[2][24576]
  int tid = threadIdx.x;
  int lane = tid & 63, wave = tid >> 6;
  int wm = wave >> 2, wn = wave & 3;  // 2M x 4N wave grid

  int nwg = gridDim.x, bid = blockIdx.x;
  int swzb = (bid & 7) * (nwg >> 3) + (bid >> 3);
  int nbn = N >> 8;
  int bm = swzb / nbn, bn = swzb % nbn;
  int r0 = bm << 7, c0 = bn << 8;  // 128 x 256 tile
  int K32 = K >> 5;
  int lbyte = (lane & 31) * 32 + (lane >> 5) * 16;  // intra-1KB-block offset

  // ---- staging precompute (tiled source, linear LDS dest) ----
  // A: 512 granules (4 m-blocks x 2 k-blocks); thread t -> granule t.
  const char* asrc;
  {
    int b = tid >> 6, mb = b >> 1, kb = b & 1;
    asrc = qx + ((size_t)((r0 >> 5) + mb) * K32 + kb) * 1024 + (tid & 63) * 16;
  }
  // B: 1024 granules (8 n-blocks x 2 k-blocks); thread t -> granules t, t+512.
  const char* bsrc0;
  const char* bsrc1;
  {
    int g = tid, b = g >> 6, nb = b >> 1, kb = b & 1;
    bsrc0 = qw + ((size_t)((c0 >> 5) + nb) * K32 + kb) * 1024 + (g & 63) * 16;
    g = tid + 512; b = g >> 6; nb = b >> 1; kb = b & 1;
    bsrc1 = qw + ((size_t)((c0 >> 5) + nb) * K32 + kb) * 1024 + (g & 63) * 16;
  }

#define BUF0 (lds_raw)
#define BUF1 (lds_raw + 24576)
#define STAGE(bufp, kt)                                                       \
  {                                                                           \
    gload_lds16(asrc + (((kt) >> 5) << 10), (bufp) + tid * 16);               \
    gload_lds16(bsrc0 + (((kt) >> 5) << 10), (bufp) + 8192 + tid * 16);       \
    gload_lds16(bsrc1 + (((kt) >> 5) << 10),                                  \
                (bufp) + 8192 + (tid + 512) * 16);                            \
  }

#define LDAI(dst, bufp, q, ks)                                                \
  dst = *(const i32x4*)((bufp) + (((wm * 2 + (q)) * 2 + (ks)) << 10) + lbyte);
#define LDBI(dst, bufp, nf, ks)                                               \
  dst = *(const i32x4*)((bufp) + 8192 +                                       \
                        (((wn * 2 + (nf)) * 2 + (ks)) << 10) + lbyte);

#define MFI(q, nf, av, bv)                                                    \
  acc[q][nf] =                                                                \
      __builtin_amdgcn_mfma_i32_32x32x32_i8(av, bv, acc[q][nf], 0, 0, 0)

  // one BK=64 K-tile: compute kt from bufc, stage ktn into bufn.
  // vmcnt(3): the 3 loads for ktn stay in flight; waits kt's loads only.
#define TILE(bufc, bufn, kt, ktn)                                             \
  {                                                                           \
    STAGE(bufn, ktn);                                                         \
    asm volatile("s_waitcnt vmcnt(3)" ::: "memory");                          \
    __builtin_amdgcn_s_barrier();                                             \
    i32x4 a00, a01, a10, a11, b00, b01, b10, b11;                             \
    LDAI(a00, bufc, 0, 0);                                                    \
    LDAI(a01, bufc, 0, 1);                                                    \
    LDAI(a10, bufc, 1, 0);                                                    \
    LDAI(a11, bufc, 1, 1);                                                    \
    LDBI(b00, bufc, 0, 0);                                                    \
    LDBI(b01, bufc, 0, 1);                                                    \
    LDBI(b10, bufc, 1, 0);                                                    \
    LDBI(b11, bufc, 1, 1);                                                    \
    asm volatile("s_waitcnt lgkmcnt(0)" ::: "memory");                        \
    __builtin_amdgcn_s_setprio(1);                                            \
    MFI(0, 0, a00, b00);                                                      \
    MFI(0, 1, a00, b10);                                                      \
    MFI(1, 0, a10, b00);                                                      \
    MFI(1, 1, a10, b10);                                                      \
    MFI(0, 0, a01, b01);                                                      \
    MFI(0, 1, a01, b11);                                                      \
    MFI(1, 0, a11, b01);                                                      \
    MFI(1, 1, a11, b11);                                                      \
    __builtin_amdgcn_s_setprio(0);                                            \
    __builtin_amdgcn_s_barrier();                                             \
  }

  i32x16 acc[2][2] = {};

  // prologue: tile 0 into buf0
  STAGE(BUF0, 0);

  int NT = K >> 6;  // 64 K-tiles; NT even
  for (int t = 0; t < NT; t += 2) {
    int kt1 = (t + 1) << 6;
    int kt2 = (t + 2) < NT ? (t + 2) << 6 : 0;  // dummy on final pair
    TILE(BUF0, BUF1, t << 6, kt1);
    TILE(BUF1, BUF0, kt1, kt2);
  }

  // drain dummy DMA before reusing LDS for outlier panels
  asm volatile("s_waitcnt vmcnt(0)" ::: "memory");
  __builtin_amdgcn_s_barrier();

  // --------- epilogue: stage outlier panels: xo 128x128B, wo 256x128B ----
#pragma unroll
  for (int i = 0; i < 2; ++i) {
    int g = tid + i * 512;  // 0..1023
    int rw = g >> 3;
    int cb = ((g & 7) ^ (rw & 7)) << 4;
    gload_lds16(xo + (size_t)(r0 + rw) * 128 + cb, lds_raw + g * 16);
  }
#pragma unroll
  for (int i = 0; i < 4; ++i) {
    int g = tid + i * 512;  // 0..2047
    int rw = g >> 3;
    int cb = ((g & 7) ^ (rw & 7)) << 4;
    gload_lds16(wo + (size_t)(c0 + rw) * 128 + cb, lds_raw + 16384 + g * 16);
  }

  // scale conversion: C/D 32x32: col=lane&31, row=(reg&3)+8*(reg>>2)+4*(lane>>5)
  f32x16 facc[2][2];
  float swv[2], bv[2];
#pragma unroll
  for (int nf = 0; nf < 2; ++nf) {
    swv[nf] = sw[c0 + wn * 64 + nf * 32 + (lane & 31)];
    bv[nf] = bias[c0 + wn * 64 + nf * 32 + (lane & 31)];
  }
#pragma unroll
  for (int q = 0; q < 2; ++q) {
    int gmb = r0 + wm * 64 + q * 32 + 4 * (lane >> 5);
    f32x4 s4a = *(const f32x4*)&sx[gmb];
    f32x4 s4b = *(const f32x4*)&sx[gmb + 8];
    f32x4 s4c = *(const f32x4*)&sx[gmb + 16];
    f32x4 s4d = *(const f32x4*)&sx[gmb + 24];
#pragma unroll
    for (int reg = 0; reg < 16; ++reg) {
      float sxv = (reg < 4) ? s4a[reg & 3]
                : (reg < 8) ? s4b[reg & 3]
                : (reg < 12) ? s4c[reg & 3] : s4d[reg & 3];
#pragma unroll
      for (int nf = 0; nf < 2; ++nf)
        facc[q][nf][reg] = (float)acc[q][nf][reg] * sxv * swv[nf];
    }
  }

  asm volatile("s_waitcnt vmcnt(0)" ::: "memory");
  __builtin_amdgcn_s_barrier();

  // outlier bf16 GEMM over K=64 into the scaled accumulators
#pragma unroll
  for (int ks = 0; ks < 4; ++ks) {
    bf16x8 ob[2];
#pragma unroll
    for (int nf = 0; nf < 2; ++nf) {
      int rn = wn * 64 + nf * 32 + (lane & 31);
      ob[nf] = *(const bf16x8*)(lds_raw + 16384 + rn * 128 +
                                (((ks * 2 + (lane >> 5)) ^ (rn & 7)) << 4));
    }
#pragma unroll
    for (int q = 0; q < 2; ++q) {
      int rl = wm * 64 + q * 32 + (lane & 31);
      bf16x8 oa = *(const bf16x8*)(lds_raw + rl * 128 +
                                   (((ks * 2 + (lane >> 5)) ^ (rl & 7)) << 4));
#pragma unroll
      for (int nf = 0; nf < 2; ++nf)
        facc[q][nf] = __builtin_amdgcn_mfma_f32_32x32x16_bf16(
            oa, ob[nf], facc[q][nf], 0, 0, 0);
    }
  }

#pragma unroll
  for (int q = 0; q < 2; ++q) {
#pragma unroll
    for (int reg = 0; reg < 16; ++reg) {
      int gm = r0 + wm * 64 + q * 32 + (reg & 3) + 8 * (reg >> 2) +
               4 * (lane >> 5);
      float* orow = out + (size_t)gm * N + c0 + wn * 64 + (lane & 31);
#pragma unroll
      for (int nf = 0; nf < 2; ++nf)
        orow[nf * 32] = facc[q][nf][reg] + bv[nf];
    }
  }
}

extern "C" void kernel_launch(void* const* d_in, const int* in_sizes, int n_in,
                              void* d_out, int out_size, void* d_ws,
                              size_t ws_size, hipStream_t stream) {
  const float* x = (const float*)d_in[0];
  const float* W = (const float*)d_in[1];
  const float* bias = (const float*)d_in[2];
  const int* thr = (const int*)d_in[3];
  float* out = (float*)d_out;

  int N = in_sizes[2];
  int K = in_sizes[1] / N;
  int M = in_sizes[0] / K;

  char* ws = (char*)d_ws;
  u32* cm = (u32*)ws;                       // K u32 (16 KB)
  int* meta = (int*)(ws + 16384);           // 65 ints
  float* sx = (float*)(ws + 32768);         // M f32
  float* sw = (float*)(ws + 32768 + (size_t)M * 4);          // N f32
  char* xo = ws + 32768 + (size_t)(M + N) * 4;               // M*64 bf16
  char* wo = xo + (size_t)M * 128;                           // N*64 bf16
  char* qx = wo + (size_t)N * 128;                           // M*K int8 tiled
  char* qw = qx + (size_t)M * K;                             // N*K int8 tiled

  k_init_cm<<<dim3((K + 255) / 256), dim3(256), 0, stream>>>(cm, K);

  {
    int gx = K / 1024;
    int gy = 128;
    int rpb = (M + gy - 1) / gy;
    k_colmax<<<dim3(gx, gy), dim3(256), 0, stream>>>(x, cm, M, K, rpb);
  }

  k_ocols<<<dim3(1), dim3(64), 0, stream>>>(cm, thr, K, meta);

  k_quant8<<<dim3(M), dim3(256), 0, stream>>>(x, cm, thr, meta, qx, sx,
                                              (u16*)xo, K, 1);
  k_quant8<<<dim3(N), dim3(256), 0, stream>>>(W, cm, thr, meta, qw, sw,
                                              (u16*)wo, K, 0);

  (void)hipFuncSetAttribute((const void*)k_gemm_i8,
                            hipFuncAttributeMaxDynamicSharedMemorySize,
                            49152);
  int nwg = (M / 128) * (N / 256);
  k_gemm_i8<<<dim3(nwg), dim3(512), 49152, stream>>>(qx, qw, sx, sw, bias,
                                                     xo, wo, out, M, N, K);
}

// Round 13
// 263.682 us; speedup vs baseline: 1.0280x; 1.0280x over previous
//
#include <hip/hip_runtime.h>

typedef unsigned short u16;
typedef unsigned char u8;
typedef unsigned int u32;
typedef __attribute__((ext_vector_type(4))) float f32x4;
typedef __attribute__((ext_vector_type(16))) float f32x16;
typedef __attribute__((ext_vector_type(8))) __bf16 bf16x8;
typedef __attribute__((ext_vector_type(4))) int i32x4;
typedef __attribute__((ext_vector_type(16))) int i32x16;

__device__ __forceinline__ u16 f2bf(float f) {
  u32 u = __float_as_uint(f);
  u32 r = (u + 0x7fffu + ((u >> 16) & 1u)) >> 16;
  return (u16)r;
}

__device__ __forceinline__ float load_thr(const int* p) {
  int iv = *p;
  float fv = __int_as_float(iv);
  if (fv >= 1.0f && fv <= 1.0e6f) return fv;
  return (float)iv;
}

__device__ __forceinline__ void gload_lds16(const void* g, void* l) {
  __builtin_amdgcn_global_load_lds(
      (const __attribute__((address_space(1))) void*)g,
      (__attribute__((address_space(3))) void*)l, 16, 0, 0);
}

// ---------------- colmax over rows of x ----------------
__global__ void k_init_cm(u32* cm, int K) {
  int i = blockIdx.x * 256 + threadIdx.x;
  if (i < K) cm[i] = 0u;
}

__global__ __launch_bounds__(256) void k_colmax(const float* __restrict__ x,
                                                u32* __restrict__ cm, int M,
                                                int K, int rpb) {
  int c4 = blockIdx.x * 256 + threadIdx.x;
  int r0 = blockIdx.y * rpb;
  int r1 = r0 + rpb;
  if (r1 > M) r1 = M;
  f32x4 mx = {0.f, 0.f, 0.f, 0.f};
  for (int r = r0; r < r1; ++r) {
    f32x4 v = *(const f32x4*)&x[(size_t)r * K + (size_t)c4 * 4];
#pragma unroll
    for (int i = 0; i < 4; ++i) mx[i] = fmaxf(mx[i], fabsf(v[i]));
  }
#pragma unroll
  for (int i = 0; i < 4; ++i)
    atomicMax(&cm[c4 * 4 + i], __float_as_uint(mx[i]));
}

// ---------------- ordered outlier-column compaction (1 wave) -------------
__global__ void k_ocols(const u32* __restrict__ cm, const int* __restrict__ thr_i,
                        int K, int* __restrict__ meta) {
  int lane = threadIdx.x;  // 64 threads
  float thr = load_thr(thr_i);
  const float* cmf = (const float*)cm;
  int per = K >> 6;
  int base = lane * per;
  int c = 0;
  for (int i = 0; i < per; ++i) c += (cmf[base + i] > thr) ? 1 : 0;
  int inc = c;
  for (int off = 1; off < 64; off <<= 1) {
    int t = __shfl_up(inc, off);
    if (lane >= off) inc += t;
  }
  int excl = inc - c;
  int total = __shfl(inc, 63);
  if (lane == 0) meta[0] = total < 64 ? total : 64;
  int idx = excl;
  for (int i = 0; i < per; ++i) {
    if (cmf[base + i] > thr) {
      if (idx < 64) meta[1 + idx] = base + i;
      idx++;
    }
  }
  for (int j = total + lane; j < 64; j += 64) meta[1 + j] = -1;
}

// ---------------- row-wise int8 quant (TILED output) + outlier gather ----
// qdst int8 tiled [rows/32][K/32][32][32] (1KB blocks, row-major in block).
__global__ __launch_bounds__(256) void k_quant8(
    const float* __restrict__ src, const u32* __restrict__ cm,
    const int* __restrict__ thr_i, const int* __restrict__ meta,
    char* __restrict__ qdst, float* __restrict__ sdst, u16* __restrict__ odst,
    int K, int zero_outlier) {
  int row = blockIdx.x;
  int tid = threadIdx.x;
  float thr = load_thr(thr_i);
  const float* sr = src + (size_t)row * K;
  const float* cmf = (const float*)cm;

  float v[16];
  u32 omask = 0;
  float lmax = 0.f;
#pragma unroll
  for (int j = 0; j < 4; ++j) {
    int c4 = j * 256 + tid;
    f32x4 val = *(const f32x4*)&sr[c4 * 4];
    f32x4 cv = *(const f32x4*)&cmf[c4 * 4];
#pragma unroll
    for (int i = 0; i < 4; ++i) {
      float xv = val[i];
      v[j * 4 + i] = xv;
      bool is_out = cv[i] > thr;
      if (is_out) omask |= 1u << (j * 4 + i);
      if (!is_out || !zero_outlier) lmax = fmaxf(lmax, fabsf(xv));
    }
  }
  float m = lmax;
#pragma unroll
  for (int off = 32; off >= 1; off >>= 1) m = fmaxf(m, __shfl_down(m, off));
  __shared__ float red[4];
  int lane = tid & 63, wv = tid >> 6;
  if (lane == 0) red[wv] = m;
  __syncthreads();
  float rm = fmaxf(fmaxf(red[0], red[1]), fmaxf(red[2], red[3]));
  float s = fmaxf(rm / 127.0f, 1e-8f);

  // tiled write: u32 index = ((row>>5)*(K>>5)+(c4>>3))*256 + (row&31)*8 + (c4&7)
  u32* qt = (u32*)qdst;
  size_t rowpart = (size_t)(row >> 5) * (K >> 5) * 256 + (size_t)(row & 31) * 8;
#pragma unroll
  for (int j = 0; j < 4; ++j) {
    int c4 = j * 256 + tid;
    u32 pk = 0;
#pragma unroll
    for (int i = 0; i < 4; ++i) {
      float xv = v[j * 4 + i];
      int iq;
      if (zero_outlier && (omask & (1u << (j * 4 + i)))) {
        iq = 0;
      } else {
        float q = rintf(xv / s);  // round-half-even, matches jnp.round
        q = fminf(fmaxf(q, -127.f), 127.f);
        iq = (int)q;
      }
      pk |= ((u32)(u8)(char)iq) << (8 * i);
    }
    qt[rowpart + (size_t)(c4 >> 3) * 256 + (c4 & 7)] = pk;
  }
  if (tid == 0) sdst[row] = s;
  if (tid < 64) {
    int n_out = meta[0];
    int oc = meta[1 + tid];
    u16 ov = 0;
    if (tid < n_out && oc >= 0) ov = f2bf(sr[oc]);
    odst[(size_t)row * 64 + tid] = ov;
  }
}

// ---------------- i8 GEMM: 128x256 block, 8 waves 2Mx4N, 64x64/wave ------
// out = sx[m]*sw[n]*(qx @ qw^T) + x_o @ w_o^T + bias
// r12 geometry (2 blocks/CU via 64-AGPR acc) + h-major LDS block layout:
// staging source permutes unit (r,h) -> LDS position h*512+r*16, so the
// MFMA frag read is byte lane*16 — fully linear, zero bank conflicts.
__global__ __launch_bounds__(512, 4) void k_gemm_i8(
    const char* __restrict__ qx, const char* __restrict__ qw,
    const float* __restrict__ sx, const float* __restrict__ sw,
    const float* __restrict__ bias, const char* __restrict__ xo,
    const char* __restrict__ wo, float* __restrict__ out, int M, int N,
    int K) {
  extern __shared__ char lds_raw[];  // 48 KB: buf[2][24576]
  int tid = threadIdx.x;
  int lane = tid & 63, wave = tid >> 6;
  int wm = wave >> 2, wn = wave & 3;  // 2M x 4N wave grid

  int nwg = gridDim.x, bid = blockIdx.x;
  int swzb = (bid & 7) * (nwg >> 3) + (bid >> 3);
  int nbn = N >> 8;
  int bm = swzb / nbn, bn = swzb % nbn;
  int r0 = bm << 7, c0 = bn << 8;  // 128 x 256 tile
  int K32 = K >> 5;

  // ---- staging precompute (tiled source, h-major permuted; LDS linear) --
  // source byte within 1KB block for dest-unit u: (u&31)*32 + (u>>5)*16
  // A: 512 granules (4 m-blocks x 2 k-blocks); thread t -> granule t.
  const char* asrc;
  {
    int b = tid >> 6, mb = b >> 1, kb = b & 1, u = tid & 63;
    asrc = qx + ((size_t)((r0 >> 5) + mb) * K32 + kb) * 1024 + (u & 31) * 32 +
           (u >> 5) * 16;
  }
  // B: 1024 granules (8 n-blocks x 2 k-blocks); thread t -> granules t, t+512.
  const char* bsrc0;
  const char* bsrc1;
  {
    int g = tid, b = g >> 6, nb = b >> 1, kb = b & 1, u = g & 63;
    bsrc0 = qw + ((size_t)((c0 >> 5) + nb) * K32 + kb) * 1024 + (u & 31) * 32 +
            (u >> 5) * 16;
    g = tid + 512; b = g >> 6; nb = b >> 1; kb = b & 1; u = g & 63;
    bsrc1 = qw + ((size_t)((c0 >> 5) + nb) * K32 + kb) * 1024 + (u & 31) * 32 +
            (u >> 5) * 16;
  }

#define BUF0 (lds_raw)
#define BUF1 (lds_raw + 24576)
#define STAGE(bufp, kt)                                                       \
  {                                                                           \
    gload_lds16(asrc + (((kt) >> 5) << 10), (bufp) + tid * 16);               \
    gload_lds16(bsrc0 + (((kt) >> 5) << 10), (bufp) + 8192 + tid * 16);       \
    gload_lds16(bsrc1 + (((kt) >> 5) << 10),                                  \
                (bufp) + 8192 + (tid + 512) * 16);                            \
  }

  // frag reads: whole wave reads its 1KB block linearly (lane*16)
#define LDAI(dst, bufp, q, ks)                                                \
  dst = *(const i32x4*)((bufp) + (((wm * 2 + (q)) * 2 + (ks)) << 10) +        \
                        lane * 16);
#define LDBI(dst, bufp, nf, ks)                                               \
  dst = *(const i32x4*)((bufp) + 8192 +                                       \
                        (((wn * 2 + (nf)) * 2 + (ks)) << 10) + lane * 16);

#define MFI(q, nf, av, bv)                                                    \
  acc[q][nf] =                                                                \
      __builtin_amdgcn_mfma_i32_32x32x32_i8(av, bv, acc[q][nf], 0, 0, 0)

  // one BK=64 K-tile: compute kt from bufc, stage ktn into bufn.
  // vmcnt(3): the 3 loads for ktn stay in flight; waits kt's loads only.
#define TILE(bufc, bufn, kt, ktn)                                             \
  {                                                                           \
    STAGE(bufn, ktn);                                                         \
    asm volatile("s_waitcnt vmcnt(3)" ::: "memory");                          \
    __builtin_amdgcn_s_barrier();                                             \
    i32x4 a00, a01, a10, a11, b00, b01, b10, b11;                             \
    LDAI(a00, bufc, 0, 0);                                                    \
    LDAI(a01, bufc, 0, 1);                                                    \
    LDAI(a10, bufc, 1, 0);                                                    \
    LDAI(a11, bufc, 1, 1);                                                    \
    LDBI(b00, bufc, 0, 0);                                                    \
    LDBI(b01, bufc, 0, 1);                                                    \
    LDBI(b10, bufc, 1, 0);                                                    \
    LDBI(b11, bufc, 1, 1);                                                    \
    asm volatile("s_waitcnt lgkmcnt(0)" ::: "memory");                        \
    __builtin_amdgcn_s_setprio(1);                                            \
    MFI(0, 0, a00, b00);                                                      \
    MFI(0, 1, a00, b10);                                                      \
    MFI(1, 0, a10, b00);                                                      \
    MFI(1, 1, a10, b10);                                                      \
    MFI(0, 0, a01, b01);                                                      \
    MFI(0, 1, a01, b11);                                                      \
    MFI(1, 0, a11, b01);                                                      \
    MFI(1, 1, a11, b11);                                                      \
    __builtin_amdgcn_s_setprio(0);                                            \
    __builtin_amdgcn_s_barrier();                                             \
  }

  i32x16 acc[2][2] = {};

  // prologue: tile 0 into buf0
  STAGE(BUF0, 0);

  int NT = K >> 6;  // 64 K-tiles; NT even
  for (int t = 0; t < NT; t += 2) {
    int kt1 = (t + 1) << 6;
    int kt2 = (t + 2) < NT ? (t + 2) << 6 : 0;  // dummy on final pair
    TILE(BUF0, BUF1, t << 6, kt1);
    TILE(BUF1, BUF0, kt1, kt2);
  }

  // drain dummy DMA before reusing LDS for outlier panels
  asm volatile("s_waitcnt vmcnt(0)" ::: "memory");
  __builtin_amdgcn_s_barrier();

  // --------- epilogue: stage outlier panels: xo 128x128B, wo 256x128B ----
#pragma unroll
  for (int i = 0; i < 2; ++i) {
    int g = tid + i * 512;  // 0..1023
    int rw = g >> 3;
    int cb = ((g & 7) ^ (rw & 7)) << 4;
    gload_lds16(xo + (size_t)(r0 + rw) * 128 + cb, lds_raw + g * 16);
  }
#pragma unroll
  for (int i = 0; i < 4; ++i) {
    int g = tid + i * 512;  // 0..2047
    int rw = g >> 3;
    int cb = ((g & 7) ^ (rw & 7)) << 4;
    gload_lds16(wo + (size_t)(c0 + rw) * 128 + cb, lds_raw + 16384 + g * 16);
  }

  // scale conversion: C/D 32x32: col=lane&31, row=(reg&3)+8*(reg>>2)+4*(lane>>5)
  f32x16 facc[2][2];
  float swv[2], bv[2];
#pragma unroll
  for (int nf = 0; nf < 2; ++nf) {
    swv[nf] = sw[c0 + wn * 64 + nf * 32 + (lane & 31)];
    bv[nf] = bias[c0 + wn * 64 + nf * 32 + (lane & 31)];
  }
#pragma unroll
  for (int q = 0; q < 2; ++q) {
    int gmb = r0 + wm * 64 + q * 32 + 4 * (lane >> 5);
    f32x4 s4a = *(const f32x4*)&sx[gmb];
    f32x4 s4b = *(const f32x4*)&sx[gmb + 8];
    f32x4 s4c = *(const f32x4*)&sx[gmb + 16];
    f32x4 s4d = *(const f32x4*)&sx[gmb + 24];
#pragma unroll
    for (int reg = 0; reg < 16; ++reg) {
      float sxv = (reg < 4) ? s4a[reg & 3]
                : (reg < 8) ? s4b[reg & 3]
                : (reg < 12) ? s4c[reg & 3] : s4d[reg & 3];
#pragma unroll
      for (int nf = 0; nf < 2; ++nf)
        facc[q][nf][reg] = (float)acc[q][nf][reg] * sxv * swv[nf];
    }
  }

  asm volatile("s_waitcnt vmcnt(0)" ::: "memory");
  __builtin_amdgcn_s_barrier();

  // outlier bf16 GEMM over K=64 into the scaled accumulators
#pragma unroll
  for (int ks = 0; ks < 4; ++ks) {
    bf16x8 ob[2];
#pragma unroll
    for (int nf = 0; nf < 2; ++nf) {
      int rn = wn * 64 + nf * 32 + (lane & 31);
      ob[nf] = *(const bf16x8*)(lds_raw + 16384 + rn * 128 +
                                (((ks * 2 + (lane >> 5)) ^ (rn & 7)) << 4));
    }
#pragma unroll
    for (int q = 0; q < 2; ++q) {
      int rl = wm * 64 + q * 32 + (lane & 31);
      bf16x8 oa = *(const bf16x8*)(lds_raw + rl * 128 +
                                   (((ks * 2 + (lane >> 5)) ^ (rl & 7)) << 4));
#pragma unroll
      for (int nf = 0; nf < 2; ++nf)
        facc[q][nf] = __builtin_amdgcn_mfma_f32_32x32x16_bf16(
            oa, ob[nf], facc[q][nf], 0, 0, 0);
    }
  }

#pragma unroll
  for (int q = 0; q < 2; ++q) {
#pragma unroll
    for (int reg = 0; reg < 16; ++reg) {
      int gm = r0 + wm * 64 + q * 32 + (reg & 3) + 8 * (reg >> 2) +
               4 * (lane >> 5);
      float* orow = out + (size_t)gm * N + c0 + wn * 64 + (lane & 31);
#pragma unroll
      for (int nf = 0; nf < 2; ++nf)
        orow[nf * 32] = facc[q][nf][reg] + bv[nf];
    }
  }
}

extern "C" void kernel_launch(void* const* d_in, const int* in_sizes, int n_in,
                              void* d_out, int out_size, void* d_ws,
                              size_t ws_size, hipStream_t stream) {
  const float* x = (const float*)d_in[0];
  const float* W = (const float*)d_in[1];
  const float* bias = (const float*)d_in[2];
  const int* thr = (const int*)d_in[3];
  float* out = (float*)d_out;

  int N = in_sizes[2];
  int K = in_sizes[1] / N;
  int M = in_sizes[0] / K;

  char* ws = (char*)d_ws;
  u32* cm = (u32*)ws;                       // K u32 (16 KB)
  int* meta = (int*)(ws + 16384);           // 65 ints
  float* sx = (float*)(ws + 32768);         // M f32
  float* sw = (float*)(ws + 32768 + (size_t)M * 4);          // N f32
  char* xo = ws + 32768 + (size_t)(M + N) * 4;               // M*64 bf16
  char* wo = xo + (size_t)M * 128;                           // N*64 bf16
  char* qx = wo + (size_t)N * 128;                           // M*K int8 tiled
  char* qw = qx + (size_t)M * K;                             // N*K int8 tiled

  k_init_cm<<<dim3((K + 255) / 256), dim3(256), 0, stream>>>(cm, K);

  {
    int gx = K / 1024;
    int gy = 128;
    int rpb = (M + gy - 1) / gy;
    k_colmax<<<dim3(gx, gy), dim3(256), 0, stream>>>(x, cm, M, K, rpb);
  }

  k_ocols<<<dim3(1), dim3(64), 0, stream>>>(cm, thr, K, meta);

  k_quant8<<<dim3(M), dim3(256), 0, stream>>>(x, cm, thr, meta, qx, sx,
                                              (u16*)xo, K, 1);
  k_quant8<<<dim3(N), dim3(256), 0, stream>>>(W, cm, thr, meta, qw, sw,
                                              (u16*)wo, K, 0);

  (void)hipFuncSetAttribute((const void*)k_gemm_i8,
                            hipFuncAttributeMaxDynamicSharedMemorySize,
                            49152);
  int nwg = (M / 128) * (N / 256);
  k_gemm_i8<<<dim3(nwg), dim3(512), 49152, stream>>>(qx, qw, sx, sw, bias,
                                                     xo, wo, out, M, N, K);
}